// Round 1
// baseline (46.613 us; speedup 1.0000x reference)
//
#include <hip/hip_runtime.h>

// NTfm3D: out[b,i,hw] = sum_k masks[b,k,hw] * (R[b,k,i,:] . points[b,:,hw] + t[b,k,i])
// B=16, K=8, HW=480*640=307200. All fp32. Memory-bound (~275 MB / dispatch).

__global__ __launch_bounds__(256) void ntfm3d_kernel(
    const float* __restrict__ points,      // [B,3,HW]
    const float* __restrict__ masks,       // [B,8,HW]
    const float* __restrict__ transforms,  // [B,8,3,4] = [B,96]
    float* __restrict__ out,               // [B,3,HW]
    int HW, int nvec)                      // nvec = HW/4
{
    __shared__ float T[96];  // transforms for this batch: 8 * (3x4)
    const int b   = blockIdx.y;
    const int tid = threadIdx.x;
    if (tid < 96) T[tid] = transforms[(size_t)b * 96 + tid];
    __syncthreads();

    const int v = blockIdx.x * 256 + tid;  // float4 index within batch
    if (v >= nvec) return;
    const int base = v * 4;

    const float* pb = points + (size_t)b * 3 * HW;
    const float* mb = masks  + (size_t)b * 8 * HW;
    float*       ob = out    + (size_t)b * 3 * HW;

    // load 4 pixels' worth of the 3 point components
    float p[3][4];
    #pragma unroll
    for (int i = 0; i < 3; ++i) {
        float4 t4 = *reinterpret_cast<const float4*>(pb + (size_t)i * HW + base);
        p[i][0] = t4.x; p[i][1] = t4.y; p[i][2] = t4.z; p[i][3] = t4.w;
    }

    float o[3][4] = {};

    #pragma unroll
    for (int k = 0; k < 8; ++k) {
        float4 m4 = *reinterpret_cast<const float4*>(mb + (size_t)k * HW + base);
        float mv[4] = {m4.x, m4.y, m4.z, m4.w};

        const float* Tk = T + k * 12;
        const float r00 = Tk[0], r01 = Tk[1], r02 = Tk[2],  t0 = Tk[3];
        const float r10 = Tk[4], r11 = Tk[5], r12 = Tk[6],  t1 = Tk[7];
        const float r20 = Tk[8], r21 = Tk[9], r22 = Tk[10], t2 = Tk[11];

        #pragma unroll
        for (int c = 0; c < 4; ++c) {
            const float s0 = fmaf(r00, p[0][c], fmaf(r01, p[1][c], fmaf(r02, p[2][c], t0)));
            const float s1 = fmaf(r10, p[0][c], fmaf(r11, p[1][c], fmaf(r12, p[2][c], t1)));
            const float s2 = fmaf(r20, p[0][c], fmaf(r21, p[1][c], fmaf(r22, p[2][c], t2)));
            o[0][c] = fmaf(mv[c], s0, o[0][c]);
            o[1][c] = fmaf(mv[c], s1, o[1][c]);
            o[2][c] = fmaf(mv[c], s2, o[2][c]);
        }
    }

    #pragma unroll
    for (int i = 0; i < 3; ++i) {
        float4 t4;
        t4.x = o[i][0]; t4.y = o[i][1]; t4.z = o[i][2]; t4.w = o[i][3];
        *reinterpret_cast<float4*>(ob + (size_t)i * HW + base) = t4;
    }
}

extern "C" void kernel_launch(void* const* d_in, const int* in_sizes, int n_in,
                              void* d_out, int out_size, void* d_ws, size_t ws_size,
                              hipStream_t stream) {
    const float* points     = (const float*)d_in[0];
    const float* masks      = (const float*)d_in[1];
    const float* transforms = (const float*)d_in[2];
    float* out = (float*)d_out;

    const int B  = in_sizes[2] / 96;          // 16
    const int HW = in_sizes[0] / (3 * B);     // 307200
    const int nvec = HW / 4;                  // 76800 (HW % 4 == 0)
    const int bx = (nvec + 255) / 256;        // 300

    dim3 grid(bx, B);
    ntfm3d_kernel<<<grid, 256, 0, stream>>>(points, masks, transforms, out, HW, nvec);
}

// Round 2
// 45.627 us; speedup vs baseline: 1.0216x; 1.0216x over previous
//
#include <hip/hip_runtime.h>

// NTfm3D: out[b,i,hw] = sum_k masks[b,k,hw] * (R[b,k,i,:] . points[b,:,hw] + t[b,k,i])
// B=16, K=8, HW=480*640=307200. All fp32. Memory-bound: inputs 216 MB (L3-resident
// if output doesn't thrash), output 59 MB. Nontemporal stores keep inputs in LLC.

__global__ __launch_bounds__(256) void ntfm3d_kernel(
    const float* __restrict__ points,      // [B,3,HW]
    const float* __restrict__ masks,       // [B,8,HW]
    const float* __restrict__ transforms,  // [B,8,3,4] = [B,96]
    float* __restrict__ out,               // [B,3,HW]
    int HW, int nvec)                      // nvec = HW/4
{
    __shared__ float T[96];  // transforms for this batch: 8 * (3x4)
    const int b   = blockIdx.y;
    const int tid = threadIdx.x;
    if (tid < 96) T[tid] = transforms[(size_t)b * 96 + tid];
    __syncthreads();

    const int v = blockIdx.x * 256 + tid;  // float4 index within batch
    if (v >= nvec) return;
    const int base = v * 4;

    const float* pb = points + (size_t)b * 3 * HW;
    const float* mb = masks  + (size_t)b * 8 * HW;
    float*       ob = out    + (size_t)b * 3 * HW;

    // load 4 pixels' worth of the 3 point components
    float p[3][4];
    #pragma unroll
    for (int i = 0; i < 3; ++i) {
        float4 t4 = *reinterpret_cast<const float4*>(pb + (size_t)i * HW + base);
        p[i][0] = t4.x; p[i][1] = t4.y; p[i][2] = t4.z; p[i][3] = t4.w;
    }

    float o[3][4] = {};

    #pragma unroll
    for (int k = 0; k < 8; ++k) {
        float4 m4 = *reinterpret_cast<const float4*>(mb + (size_t)k * HW + base);
        float mv[4] = {m4.x, m4.y, m4.z, m4.w};

        const float* Tk = T + k * 12;
        const float r00 = Tk[0], r01 = Tk[1], r02 = Tk[2],  t0 = Tk[3];
        const float r10 = Tk[4], r11 = Tk[5], r12 = Tk[6],  t1 = Tk[7];
        const float r20 = Tk[8], r21 = Tk[9], r22 = Tk[10], t2 = Tk[11];

        #pragma unroll
        for (int c = 0; c < 4; ++c) {
            const float s0 = fmaf(r00, p[0][c], fmaf(r01, p[1][c], fmaf(r02, p[2][c], t0)));
            const float s1 = fmaf(r10, p[0][c], fmaf(r11, p[1][c], fmaf(r12, p[2][c], t1)));
            const float s2 = fmaf(r20, p[0][c], fmaf(r21, p[1][c], fmaf(r22, p[2][c], t2)));
            o[0][c] = fmaf(mv[c], s0, o[0][c]);
            o[1][c] = fmaf(mv[c], s1, o[1][c]);
            o[2][c] = fmaf(mv[c], s2, o[2][c]);
        }
    }

    // Nontemporal stores: don't let the 59 MB output stream evict the
    // 216 MB input set from the 256 MiB Infinity Cache.
    #pragma unroll
    for (int i = 0; i < 3; ++i) {
        float* dst = ob + (size_t)i * HW + base;
        __builtin_nontemporal_store(o[i][0], dst + 0);
        __builtin_nontemporal_store(o[i][1], dst + 1);
        __builtin_nontemporal_store(o[i][2], dst + 2);
        __builtin_nontemporal_store(o[i][3], dst + 3);
    }
}

extern "C" void kernel_launch(void* const* d_in, const int* in_sizes, int n_in,
                              void* d_out, int out_size, void* d_ws, size_t ws_size,
                              hipStream_t stream) {
    const float* points     = (const float*)d_in[0];
    const float* masks      = (const float*)d_in[1];
    const float* transforms = (const float*)d_in[2];
    float* out = (float*)d_out;

    const int B  = in_sizes[2] / 96;          // 16
    const int HW = in_sizes[0] / (3 * B);     // 307200
    const int nvec = HW / 4;                  // 76800 (HW % 4 == 0)
    const int bx = (nvec + 255) / 256;        // 300

    dim3 grid(bx, B);
    ntfm3d_kernel<<<grid, 256, 0, stream>>>(points, masks, transforms, out, HW, nvec);
}